// Round 1
// baseline (113.115 us; speedup 1.0000x reference)
//
#include <hip/hip_runtime.h>

#define PCX 512.0f
#define PCY 512.0f

// ---------------------------------------------------------------------------
// Setup: compose R = Rx(a) @ Ry(b) @ Rz(c) and pack [R(9), t(3)] per view.
// Derivation (matches the JAX reference exactly in structure):
//   row0 = [ cb*cc,            -cb*sc,            sb    ]
//   row1 = [ ca*sc + sa*sb*cc,  ca*cc - sa*sb*sc, -sa*cb]
//   row2 = [ sa*sc - ca*sb*cc,  sa*cc + ca*sb*sc,  ca*cb]
// ---------------------------------------------------------------------------
__global__ void setup_R_kernel(const float* __restrict__ eulers,
                               const float* __restrict__ trans,
                               float* __restrict__ Rt, int V) {
    int v = blockIdx.x * blockDim.x + threadIdx.x;
    if (v >= V) return;
    float a = eulers[3 * v + 0], b = eulers[3 * v + 1], c = eulers[3 * v + 2];
    float sa, ca, sb, cb, sc, cc;
    sincosf(a, &sa, &ca);
    sincosf(b, &sb, &cb);
    sincosf(c, &sc, &cc);
    float* o = Rt + 12 * v;
    o[0] = cb * cc;                 o[1] = -cb * sc;                o[2] = sb;
    o[3] = ca * sc + sa * sb * cc;  o[4] = ca * cc - sa * sb * sc;  o[5] = -sa * cb;
    o[6] = sa * sc - ca * sb * cc;  o[7] = sa * cc + ca * sb * sc;  o[8] = ca * cb;
    o[9] = trans[3 * v + 0];        o[10] = trans[3 * v + 1];       o[11] = trans[3 * v + 2];
}

// ---------------------------------------------------------------------------
// Main projection kernel. grid = (ceil(N/256), V). One thread per (v, n).
// Writes: float2 (u,v) coalesced + float Z coalesced. Reads: float3 point
// (dwordx3, L2-resident) + wave-uniform camera params (scalar loads).
// ---------------------------------------------------------------------------
template <bool USE_WS>
__global__ void __launch_bounds__(256)
proj_kernel(const float* __restrict__ pts,
            const float* __restrict__ Rt,
            const float* __restrict__ eulers,
            const float* __restrict__ trans,
            const float* __restrict__ focal_p,
            float2* __restrict__ uv,
            float* __restrict__ zout,
            int N) {
    __shared__ float sRt[12];
    const int v = blockIdx.y;

    if (!USE_WS) {
        if (threadIdx.x == 0) {
            float a = eulers[3 * v + 0], b = eulers[3 * v + 1], c = eulers[3 * v + 2];
            float sa, ca, sb, cb, sc, cc;
            sincosf(a, &sa, &ca);
            sincosf(b, &sb, &cb);
            sincosf(c, &sc, &cc);
            sRt[0] = cb * cc;                sRt[1] = -cb * sc;               sRt[2] = sb;
            sRt[3] = ca * sc + sa * sb * cc; sRt[4] = ca * cc - sa * sb * sc; sRt[5] = -sa * cb;
            sRt[6] = sa * sc - ca * sb * cc; sRt[7] = sa * cc + ca * sb * sc; sRt[8] = ca * cb;
            sRt[9] = trans[3 * v + 0];       sRt[10] = trans[3 * v + 1];      sRt[11] = trans[3 * v + 2];
        }
        __syncthreads();
    }

    const int n = blockIdx.x * blockDim.x + threadIdx.x;
    if (n >= N) return;

    const float* p = USE_WS ? (Rt + 12 * v) : sRt;
    const float f = *focal_p;

    const float3 P = reinterpret_cast<const float3*>(pts)[n];

    const float X = fmaf(p[0], P.x, fmaf(p[1], P.y, fmaf(p[2], P.z, p[9])));
    const float Y = fmaf(p[3], P.x, fmaf(p[4], P.y, fmaf(p[5], P.z, p[10])));
    const float Z = fmaf(p[6], P.x, fmaf(p[7], P.y, fmaf(p[8], P.z, p[11])));

    const float q = 1.0f / Z;                 // IEEE divide, shared by u and v
    const float u  = fmaf(-f * X, q, PCX);
    const float vv = fmaf( f * Y, q, PCY);

    const size_t idx = (size_t)v * N + n;
    uv[idx]   = make_float2(u, vv);
    zout[idx] = Z;
}

extern "C" void kernel_launch(void* const* d_in, const int* in_sizes, int n_in,
                              void* d_out, int out_size, void* d_ws, size_t ws_size,
                              hipStream_t stream) {
    const float* focal  = (const float*)d_in[0];
    const float* eulers = (const float*)d_in[1];
    const float* trans  = (const float*)d_in[2];
    const float* pts    = (const float*)d_in[3];

    const int V = in_sizes[1] / 3;
    const int N = in_sizes[3] / 3;

    float*  out = (float*)d_out;
    float2* uv  = (float2*)out;
    float*  z   = out + (size_t)2 * V * N;

    dim3 block(256, 1, 1);
    dim3 grid((N + 255) / 256, V, 1);

    const size_t need = (size_t)V * 12 * sizeof(float);
    if (ws_size >= need) {
        float* Rt = (float*)d_ws;
        setup_R_kernel<<<dim3((V + 63) / 64), dim3(64), 0, stream>>>(eulers, trans, Rt, V);
        proj_kernel<true><<<grid, block, 0, stream>>>(pts, Rt, eulers, trans, focal, uv, z, N);
    } else {
        proj_kernel<false><<<grid, block, 0, stream>>>(pts, nullptr, eulers, trans, focal, uv, z, N);
    }
}